// Round 4
// baseline (111.278 us; speedup 1.0000x reference)
//
#include <hip/hip_runtime.h>
#include <hip/hip_bf16.h>
#include <math.h>

#define N_NODES 2048
#define F_DIM   128
#define H_HEADS 4
#define B_BATCH 8
#define LEAKY   0.2f

typedef float f32x4 __attribute__((ext_vector_type(4)));
typedef float f32x2 __attribute__((ext_vector_type(2)));

__device__ __forceinline__ float tanh_fast(float x) {
    const float e = __expf(2.0f * x);
    return 1.0f - 2.0f / (e + 1.0f);
}

// ---------------- Kernel 0: bitpack A (134 MB -> 4 MB) ----------------
// byte b of a row covers columns [b*8, b*8+8), bit k <-> column b*8+k.
// Little-endian: dword w read later gives bit t <-> column w*32+t.
__global__ __launch_bounds__(256) void gat_bitpack(const float* __restrict__ A,
                                                   unsigned char* __restrict__ maskb) {
    const int row = blockIdx.x;
    const int tid = threadIdx.x;
    const f32x4* Ar = (const f32x4*)(A + (size_t)row * N_NODES);
    const f32x4 a0 = __builtin_nontemporal_load(Ar + tid * 2);
    const f32x4 a1 = __builtin_nontemporal_load(Ar + tid * 2 + 1);
    unsigned b = 0;
    b |= (a0.x != 0.0f ? 1u : 0u) << 0;
    b |= (a0.y != 0.0f ? 1u : 0u) << 1;
    b |= (a0.z != 0.0f ? 1u : 0u) << 2;
    b |= (a0.w != 0.0f ? 1u : 0u) << 3;
    b |= (a1.x != 0.0f ? 1u : 0u) << 4;
    b |= (a1.y != 0.0f ? 1u : 0u) << 5;
    b |= (a1.z != 0.0f ? 1u : 0u) << 6;
    b |= (a1.w != 0.0f ? 1u : 0u) << 7;
    maskb[(size_t)row * 256 + tid] = (unsigned char)b;
}

// ---------------- Kernel 1: projections, packed [b][n][h] ----------------
__global__ __launch_bounds__(256) void gat_proj(const float* __restrict__ X,
                                                const float* __restrict__ wS,
                                                const float* __restrict__ wN,
                                                float* __restrict__ aSt,
                                                float* __restrict__ aNt) {
    const int wave = threadIdx.x >> 6;
    const int lane = threadIdx.x & 63;
    const int row  = blockIdx.x * 4 + wave;            // b*N + n
    const float* xr = X + (size_t)row * F_DIM;
    const float x0 = xr[lane];
    const float x1 = xr[lane + 64];
    float4 ps4, pn4;
    float* psv = (float*)&ps4;
    float* pnv = (float*)&pn4;
#pragma unroll
    for (int h = 0; h < H_HEADS; ++h) {
        float ps = x0 * wS[h * F_DIM + lane] + x1 * wS[h * F_DIM + 64 + lane];
        float pn = x0 * wN[h * F_DIM + lane] + x1 * wN[h * F_DIM + 64 + lane];
#pragma unroll
        for (int off = 32; off > 0; off >>= 1) {
            ps += __shfl_xor(ps, off);
            pn += __shfl_xor(pn, off);
        }
        psv[h] = ps;
        pnv[h] = pn;
    }
    if (lane == 0) {
        ((float4*)aSt)[row] = ps4;
        ((float4*)aNt)[row] = pn4;
    }
}

// ---------------- Kernel 1b: per-(b,h) global max of a_neigh ----------------
__global__ __launch_bounds__(256) void gat_gmax(const float* __restrict__ aNt,
                                                float* __restrict__ gmax) {
    const int b = blockIdx.x;
    const int tid = threadIdx.x;
    const int lane = tid & 63;
    const int wv = tid >> 6;
    __shared__ float4 s_part[4];
    float4 m = make_float4(-1e30f, -1e30f, -1e30f, -1e30f);
    const float4* src = (const float4*)aNt + (size_t)b * N_NODES;
    for (int n = tid; n < N_NODES; n += 256) {
        const float4 v = src[n];
        m.x = fmaxf(m.x, v.x); m.y = fmaxf(m.y, v.y);
        m.z = fmaxf(m.z, v.z); m.w = fmaxf(m.w, v.w);
    }
#pragma unroll
    for (int off = 32; off > 0; off >>= 1) {
        m.x = fmaxf(m.x, __shfl_xor(m.x, off));
        m.y = fmaxf(m.y, __shfl_xor(m.y, off));
        m.z = fmaxf(m.z, __shfl_xor(m.z, off));
        m.w = fmaxf(m.w, __shfl_xor(m.w, off));
    }
    if (lane == 0) s_part[wv] = m;
    __syncthreads();
    if (tid == 0) {
        float4 r = s_part[0];
#pragma unroll
        for (int w = 1; w < 4; ++w) {
            r.x = fmaxf(r.x, s_part[w].x); r.y = fmaxf(r.y, s_part[w].y);
            r.z = fmaxf(r.z, s_part[w].z); r.w = fmaxf(r.w, s_part[w].w);
        }
        ((float4*)gmax)[b] = r;
    }
}

// 16-FMA microtile: 4 heads x 4 feature floats
#define FMA16(PV, XV)                                        \
    do {                                                     \
        acc[0][0] = fmaf((PV).x, (XV).x, acc[0][0]);         \
        acc[0][1] = fmaf((PV).x, (XV).y, acc[0][1]);         \
        acc[0][2] = fmaf((PV).x, (XV).z, acc[0][2]);         \
        acc[0][3] = fmaf((PV).x, (XV).w, acc[0][3]);         \
        acc[1][0] = fmaf((PV).y, (XV).x, acc[1][0]);         \
        acc[1][1] = fmaf((PV).y, (XV).y, acc[1][1]);         \
        acc[1][2] = fmaf((PV).y, (XV).z, acc[1][2]);         \
        acc[1][3] = fmaf((PV).y, (XV).w, acc[1][3]);         \
        acc[2][0] = fmaf((PV).z, (XV).x, acc[2][0]);         \
        acc[2][1] = fmaf((PV).z, (XV).y, acc[2][1]);         \
        acc[2][2] = fmaf((PV).z, (XV).z, acc[2][2]);         \
        acc[2][3] = fmaf((PV).z, (XV).w, acc[2][3]);         \
        acc[3][0] = fmaf((PV).w, (XV).x, acc[3][0]);         \
        acc[3][1] = fmaf((PV).w, (XV).y, acc[3][1]);         \
        acc[3][2] = fmaf((PV).w, (XV).z, acc[3][2]);         \
        acc[3][3] = fmaf((PV).w, (XV).w, acc[3][3]);         \
    } while (0)

// ---------------- Kernel 2: sparse softmax-gather per (b,n) row ----------------
// Mask-based phase 1 (reads 256 B of bitmask instead of 8 KB of A).
__global__ __launch_bounds__(256, 6) void gat_main(const float* __restrict__ X,
                                                   const unsigned* __restrict__ maskw,
                                                   const float* __restrict__ aSt,
                                                   const float* __restrict__ aNt,
                                                   const float* __restrict__ gmax,
                                                   float* __restrict__ out) {
    const int tid = threadIdx.x;
    // batch-per-XCD swizzle: XCD k runs exactly batch k (keeps X_b L2-resident).
    const int bid = blockIdx.x;
    const int row = ((bid & 7) << 11) | (bid >> 3);   // b*N + n
    const int b = row >> 11;
    const int lane = tid & 63;
    const int wv = tid >> 6;

    __shared__ short  s_idx[N_NODES];           // compacted neighbor indices (sorted)
    __shared__ float4 s_p4[256];                // p for chunk: [entry][head]
    __shared__ int    s_off[256];               // X-row byte offsets for chunk
    __shared__ float  s_red[4 * 512];           // per-wave partial sums
    __shared__ float  s_M[4];
    __shared__ float  s_sv[4];
    __shared__ float  s_scr[16];                // [wv][h] lsum partials
    __shared__ int    s_cnt;

    // ---- Phase 1: popcount-scan of 64 mask dwords (wave 0 only) ----
    unsigned mw = 0;
    if (tid < 64) mw = maskw[(size_t)row * 64 + tid];

    // per-head shift constants on wave 1 (parallel with wave-0 scan)
    if (tid >= 64 && tid < 68) {
        const int t = tid - 64;
        const float sv = aSt[(size_t)row * 4 + t];
        const float g = gmax[b * 4 + t];
        float v = sv + g;
        v = fmaxf(v, LEAKY * v);                // leaky, monotonic -> valid upper bound
        s_M[t] = v;
        s_sv[t] = sv;
    }

    if (tid < 64) {
        const int c = __popc(mw);
        int incl = c;
#pragma unroll
        for (int d = 1; d < 64; d <<= 1) {
            const int u = __shfl_up(incl, d);
            if (lane >= d) incl += u;
        }
        if (lane == 63) s_cnt = incl;
        int p = incl - c;                       // exclusive prefix
        unsigned m = mw;
        while (m) {
            const int bpos = __ffs(m) - 1;
            s_idx[p++] = (short)((lane << 5) + bpos);
            m &= m - 1;
        }
    }
    __syncthreads();
    const int cnt = s_cnt;

    // ---- Phase 2: chunked p-generation + gather-accumulate ----
    float acc[4][4];
#pragma unroll
    for (int h = 0; h < 4; ++h)
#pragma unroll
        for (int fi = 0; fi < 4; ++fi) acc[h][fi] = 0.0f;
    float lsum[4] = {0.0f, 0.0f, 0.0f, 0.0f};

    const int jsub = tid >> 5;                  // 0..7
    const int f4 = tid & 31;                    // 0..31
    const char* XbB = (const char*)(X + (size_t)b * N_NODES * F_DIM) + (f4 << 4);
    const float4* aNb4 = (const float4*)aNt + (size_t)b * N_NODES;

    for (int base = 0; base < cnt; base += 256) {
        const int clen = min(256, cnt - base);
        if (tid < clen) {
            const int m = s_idx[base + tid];
            const float4 t = aNb4[m];
            const float tv[4] = {t.x, t.y, t.z, t.w};
            float4 p4;
            float* pp = (float*)&p4;
#pragma unroll
            for (int h = 0; h < H_HEADS; ++h) {
                float v = s_sv[h] + tv[h];
                v = fmaxf(v, LEAKY * v);
                const float p = __expf(v - s_M[h]);
                pp[h] = p;
                lsum[h] += p;
            }
            s_p4[tid] = p4;
            s_off[tid] = m << 9;                // byte offset of X row
        }
        __syncthreads();
#pragma unroll 4
        for (int j = jsub; j < clen; j += 8) {
            const float4 pv = s_p4[j];
            const float4 xv = *(const float4*)(XbB + (unsigned)s_off[j]);
            FMA16(pv, xv);
        }
        __syncthreads();
    }

    // ---- Phase 3: reductions + output ----
#pragma unroll
    for (int h = 0; h < H_HEADS; ++h) {
        float v = lsum[h];
#pragma unroll
        for (int off = 32; off > 0; off >>= 1) v += __shfl_xor(v, off);
        if (lane == 0) s_scr[wv * 4 + h] = v;
    }
#pragma unroll
    for (int h = 0; h < 4; ++h)
#pragma unroll
        for (int fi = 0; fi < 4; ++fi)
            acc[h][fi] += __shfl_xor(acc[h][fi], 32);
    if (lane < 32) {
        float4* red4 = (float4*)s_red;
#pragma unroll
        for (int h = 0; h < 4; ++h)
            red4[wv * 128 + h * 32 + f4] =
                make_float4(acc[h][0], acc[h][1], acc[h][2], acc[h][3]);
    }
    __syncthreads();

    const int hf = tid * 2;
    const int h = tid >> 6;                     // == hf>>7
    const float l = s_scr[h] + s_scr[4 + h] + s_scr[8 + h] + s_scr[12 + h];
    const float invl = 1.0f / l;
    float v0 = 0.0f, v1 = 0.0f;
#pragma unroll
    for (int w = 0; w < 4; ++w) {
        v0 += s_red[w * 512 + hf];
        v1 += s_red[w * 512 + hf + 1];
    }
    f32x2 o;
    o.x = tanh_fast(v0 * invl);
    o.y = tanh_fast(v1 * invl);
    __builtin_nontemporal_store(o, (f32x2*)&out[(size_t)row * 512 + hf]);
}

// ---------------- Fallback kernel (round-3 version, reads A directly) ----------------
__global__ __launch_bounds__(256, 6) void gat_main_fb(const float* __restrict__ X,
                                                      const float* __restrict__ A,
                                                      const float* __restrict__ aSt,
                                                      const float* __restrict__ aNt,
                                                      const float* __restrict__ gmax,
                                                      float* __restrict__ out) {
    const int tid = threadIdx.x;
    const int bid = blockIdx.x;
    const int row = ((bid & 7) << 11) | (bid >> 3);
    const int b = row >> 11;
    const int lane = tid & 63;
    const int wv = tid >> 6;

    __shared__ short  s_idx[N_NODES];
    __shared__ float4 s_p4[256];
    __shared__ int    s_off[256];
    __shared__ float  s_red[4 * 512];
    __shared__ int    s_wtot[4];
    __shared__ float  s_M[4];
    __shared__ float  s_sv[4];
    __shared__ float  s_scr[16];

    const f32x4* Arow = (const f32x4*)(A + (size_t)row * N_NODES);
    const f32x4 a0 = __builtin_nontemporal_load(Arow + tid * 2);
    const f32x4 a1 = __builtin_nontemporal_load(Arow + tid * 2 + 1);

    if (tid < 4) {
        const float sv = aSt[(size_t)row * 4 + tid];
        const float g = gmax[b * 4 + tid];
        float v = sv + g;
        v = fmaxf(v, LEAKY * v);
        s_M[tid] = v;
        s_sv[tid] = sv;
    }

    const float av[8] = {a0.x, a0.y, a0.z, a0.w, a1.x, a1.y, a1.z, a1.w};
    int c = 0;
#pragma unroll
    for (int k = 0; k < 8; ++k) c += (av[k] != 0.0f) ? 1 : 0;

    int incl = c;
#pragma unroll
    for (int d = 1; d < 64; d <<= 1) {
        const int u = __shfl_up(incl, d);
        if (lane >= d) incl += u;
    }
    if (lane == 63) s_wtot[wv] = incl;
    __syncthreads();
    int wbase = 0;
#pragma unroll
    for (int w = 0; w < 4; ++w) wbase += (w < wv) ? s_wtot[w] : 0;
    const int cnt = s_wtot[0] + s_wtot[1] + s_wtot[2] + s_wtot[3];
    int pos = wbase + (incl - c);
#pragma unroll
    for (int k = 0; k < 8; ++k) {
        if (av[k] != 0.0f) s_idx[pos++] = (short)(tid * 8 + k);
    }
    __syncthreads();

    float acc[4][4];
#pragma unroll
    for (int h = 0; h < 4; ++h)
#pragma unroll
        for (int fi = 0; fi < 4; ++fi) acc[h][fi] = 0.0f;
    float lsum[4] = {0.0f, 0.0f, 0.0f, 0.0f};

    const int jsub = tid >> 5;
    const int f4 = tid & 31;
    const char* XbB = (const char*)(X + (size_t)b * N_NODES * F_DIM) + (f4 << 4);
    const float4* aNb4 = (const float4*)aNt + (size_t)b * N_NODES;

    for (int base = 0; base < cnt; base += 256) {
        const int clen = min(256, cnt - base);
        if (tid < clen) {
            const int m = s_idx[base + tid];
            const float4 t = aNb4[m];
            const float tv[4] = {t.x, t.y, t.z, t.w};
            float4 p4;
            float* pp = (float*)&p4;
#pragma unroll
            for (int h = 0; h < H_HEADS; ++h) {
                float v = s_sv[h] + tv[h];
                v = fmaxf(v, LEAKY * v);
                const float p = __expf(v - s_M[h]);
                pp[h] = p;
                lsum[h] += p;
            }
            s_p4[tid] = p4;
            s_off[tid] = m << 9;
        }
        __syncthreads();
#pragma unroll 4
        for (int j = jsub; j < clen; j += 8) {
            const float4 pv = s_p4[j];
            const float4 xv = *(const float4*)(XbB + (unsigned)s_off[j]);
            FMA16(pv, xv);
        }
        __syncthreads();
    }

#pragma unroll
    for (int h = 0; h < H_HEADS; ++h) {
        float v = lsum[h];
#pragma unroll
        for (int off = 32; off > 0; off >>= 1) v += __shfl_xor(v, off);
        if (lane == 0) s_scr[wv * 4 + h] = v;
    }
#pragma unroll
    for (int h = 0; h < 4; ++h)
#pragma unroll
        for (int fi = 0; fi < 4; ++fi)
            acc[h][fi] += __shfl_xor(acc[h][fi], 32);
    if (lane < 32) {
        float4* red4 = (float4*)s_red;
#pragma unroll
        for (int h = 0; h < 4; ++h)
            red4[wv * 128 + h * 32 + f4] =
                make_float4(acc[h][0], acc[h][1], acc[h][2], acc[h][3]);
    }
    __syncthreads();

    const int hf = tid * 2;
    const int h = tid >> 6;
    const float l = s_scr[h] + s_scr[4 + h] + s_scr[8 + h] + s_scr[12 + h];
    const float invl = 1.0f / l;
    float v0 = 0.0f, v1 = 0.0f;
#pragma unroll
    for (int w = 0; w < 4; ++w) {
        v0 += s_red[w * 512 + hf];
        v1 += s_red[w * 512 + hf + 1];
    }
    f32x2 o;
    o.x = tanh_fast(v0 * invl);
    o.y = tanh_fast(v1 * invl);
    __builtin_nontemporal_store(o, (f32x2*)&out[(size_t)row * 512 + hf]);
}

extern "C" void kernel_launch(void* const* d_in, const int* in_sizes, int n_in,
                              void* d_out, int out_size, void* d_ws, size_t ws_size,
                              hipStream_t stream) {
    const float* X  = (const float*)d_in[0];
    const float* A  = (const float*)d_in[1];
    const float* wS = (const float*)d_in[2];
    const float* wN = (const float*)d_in[3];
    float* out = (float*)d_out;

    float* aSt = (float*)d_ws;                                  // B*N*H floats (packed)
    float* aNt = aSt + (size_t)B_BATCH * N_NODES * H_HEADS;     // B*N*H floats
    float* gmx = aNt + (size_t)B_BATCH * N_NODES * H_HEADS;     // B*H floats
    unsigned char* maskb = (unsigned char*)(gmx + B_BATCH * H_HEADS);

    const size_t need = ((size_t)B_BATCH * N_NODES * H_HEADS * 2 + B_BATCH * H_HEADS) * 4
                        + (size_t)B_BATCH * N_NODES * (N_NODES / 8);

    gat_proj<<<(B_BATCH * N_NODES) / 4, 256, 0, stream>>>(X, wS, wN, aSt, aNt);
    gat_gmax<<<B_BATCH, 256, 0, stream>>>(aNt, gmx);
    if (ws_size >= need) {
        gat_bitpack<<<B_BATCH * N_NODES, 256, 0, stream>>>(A, maskb);
        gat_main<<<B_BATCH * N_NODES, 256, 0, stream>>>(X, (const unsigned*)maskb,
                                                        aSt, aNt, gmx, out);
    } else {
        gat_main_fb<<<B_BATCH * N_NODES, 256, 0, stream>>>(X, A, aSt, aNt, gmx, out);
    }
}